// Round 1
// baseline (119.961 us; speedup 1.0000x reference)
//
#include <hip/hip_runtime.h>
#include <math.h>

#define IN_DIM  256
#define OUT_DIM 256
#define NROWS   68     // G + K
#define NT      71     // knot count
#define BATCH   512

// out[b,o] = sum_c [ sum_{j=0..3} N_j(x[b,c]) * w[i(b,c)-3+j, c, o] + silu(x[b,c]) * w[67, c, o] ]
__global__ __launch_bounds__(256) void kan_gather_kernel(
    const float* __restrict__ x, const float* __restrict__ w,
    const float* __restrict__ t, float* __restrict__ out) {
  __shared__ float  lt[NT];
  __shared__ float4 lyv[IN_DIM];   // N0..N3 basis values per c
  __shared__ float  lys[IN_DIM];   // silu(x) per c
  __shared__ int    lbase[IN_DIM]; // i-3 per c
  __shared__ float4 red4[4][64];   // c-slice partial reduction

  const int tid = threadIdx.x;
  const int b   = blockIdx.x;

  if (tid < NT) lt[tid] = t[tid];
  __syncthreads();

  // ---- Phase 1: basis for c = tid (exact Cox-de Boor, k=4) ----
  {
    const int c = tid;
    const float xv = x[b * IN_DIM + c];
    // initial guess from uniform interior knots (h = 2/64), then exact fix-up
    int i = 3 + (int)floorf((xv + 1.0f) * 32.0f);
    i = i < 3 ? 3 : (i > 66 ? 66 : i);
    while (i > 3 && xv < lt[i]) --i;          // move down until t[i] <= x
    while (i < 66 && xv >= lt[i + 1]) ++i;    // move up until x < t[i+1]
    // i == clamp(searchsorted(t, x, 'right') - 1, 3, 66)

    float N0 = 1.f, N1 = 0.f, N2 = 0.f, N3 = 0.f;
    // p = 1
    {
      const float l1 = xv - lt[i];
      const float r1 = lt[i + 1] - xv;
      const float d0 = r1 + l1;
      const float tp = N0 / d0;
      N1 = l1 * tp;
      N0 = r1 * tp;
    }
    // p = 2
    {
      const float l1 = xv - lt[i];
      const float l2 = xv - lt[i - 1];
      const float r1 = lt[i + 1] - xv;
      const float r2 = lt[i + 2] - xv;
      float saved = 0.f;
      const float d0 = r1 + l2; const float tp0 = N0 / d0;
      const float n0 = saved + r1 * tp0; saved = l2 * tp0;
      const float d1 = r2 + l1; const float tp1 = N1 / d1;
      const float n1 = saved + r2 * tp1; saved = l1 * tp1;
      N0 = n0; N1 = n1; N2 = saved;
    }
    // p = 3
    {
      const float l1 = xv - lt[i];
      const float l2 = xv - lt[i - 1];
      const float l3 = xv - lt[i - 2];
      const float r1 = lt[i + 1] - xv;
      const float r2 = lt[i + 2] - xv;
      const float r3 = lt[i + 3] - xv;
      float saved = 0.f;
      const float d0 = r1 + l3; const float tp0 = N0 / d0;
      const float n0 = saved + r1 * tp0; saved = l3 * tp0;
      const float d1 = r2 + l2; const float tp1 = N1 / d1;
      const float n1 = saved + r2 * tp1; saved = l2 * tp1;
      const float d2 = r3 + l1; const float tp2 = N2 / d2;
      const float n2 = saved + r3 * tp2; saved = l1 * tp2;
      N0 = n0; N1 = n1; N2 = n2; N3 = saved;
    }
    lyv[c]   = make_float4(N0, N1, N2, N3);
    lys[c]   = xv / (1.0f + expf(-xv));
    lbase[c] = i - 3;
  }
  __syncthreads();

  // ---- Phase 2: gather-accumulate. thread = (oq in [0,64), cslice in [0,4)) ----
  const int oq = tid & 63;   // float4 index over OUT_DIM
  const int cs = tid >> 6;   // c-slice (whole wave shares one slice)
  const float4* __restrict__ w4 = (const float4*)w;  // idx: row*16384 + c*64 + oq

  float4 acc = make_float4(0.f, 0.f, 0.f, 0.f);
  const int cbeg = cs * 64;
  #pragma unroll 4
  for (int m = 0; m < 64; ++m) {
    const int c = cbeg + m;
    const float4 yv = lyv[c];       // LDS broadcast (same addr across wave)
    const float  ys = lys[c];
    const int base  = lbase[c];
    const float4* p = w4 + c * 64 + oq;
    const float4 a0 = p[(base + 0) * 16384];
    const float4 a1 = p[(base + 1) * 16384];
    const float4 a2 = p[(base + 2) * 16384];
    const float4 a3 = p[(base + 3) * 16384];
    const float4 a4 = p[67 * 16384];
    acc.x += yv.x * a0.x + yv.y * a1.x + yv.z * a2.x + yv.w * a3.x + ys * a4.x;
    acc.y += yv.x * a0.y + yv.y * a1.y + yv.z * a2.y + yv.w * a3.y + ys * a4.y;
    acc.z += yv.x * a0.z + yv.y * a1.z + yv.z * a2.z + yv.w * a3.z + ys * a4.z;
    acc.w += yv.x * a0.w + yv.y * a1.w + yv.z * a2.w + yv.w * a3.w + ys * a4.w;
  }

  // ---- Phase 3: reduce the 4 c-slices, write out ----
  red4[cs][oq] = acc;
  __syncthreads();
  if (cs == 0) {
    const float4 p0 = red4[0][oq];
    const float4 p1 = red4[1][oq];
    const float4 p2 = red4[2][oq];
    const float4 p3 = red4[3][oq];
    float4 s;
    s.x = (p0.x + p1.x) + (p2.x + p3.x);
    s.y = (p0.y + p1.y) + (p2.y + p3.y);
    s.z = (p0.z + p1.z) + (p2.z + p3.z);
    s.w = (p0.w + p1.w) + (p2.w + p3.w);
    ((float4*)out)[b * 64 + oq] = s;
  }
}

extern "C" void kernel_launch(void* const* d_in, const int* in_sizes, int n_in,
                              void* d_out, int out_size, void* d_ws, size_t ws_size,
                              hipStream_t stream) {
  const float* x = (const float*)d_in[0];
  const float* w = (const float*)d_in[1];
  const float* t = (const float*)d_in[2];
  float* out = (float*)d_out;
  kan_gather_kernel<<<BATCH, 256, 0, stream>>>(x, w, t, out);
}

// Round 2
// 95.414 us; speedup vs baseline: 1.2573x; 1.2573x over previous
//
#include <hip/hip_runtime.h>
#include <math.h>

#define IN_DIM  256
#define OUT_DIM 256
#define NROWS   68     // G + K
#define NT      71     // knot count
#define BATCH   512

// out[b,o] = sum_c [ sum_{j=0..3} N_j(x[b,c]) * w[i(b,c)-3+j, c, o] + silu(x[b,c]) * w[67, c, o] ]
// Grid: 2048 blocks = (b, c-slice). Each block: 64 c's. Partials -> atomicAdd(out).
__global__ __launch_bounds__(256) void kan_gather_kernel(
    const float* __restrict__ x, const float* __restrict__ w,
    const float* __restrict__ t, float* __restrict__ out) {
  __shared__ float  lt[NT];
  __shared__ float4 lyv[64];    // N0..N3 basis values per local c
  __shared__ float  lys[64];    // silu(x) per local c
  __shared__ int    lbase[64];  // i-3 per local c
  __shared__ float4 red4[4][64];

  const int tid = threadIdx.x;
  const unsigned bid = blockIdx.x;
  // XCD-affine swizzle: slice = (xcd >> 1), so each c-slice's ~4.4 MB weight
  // region is served by 2 XCDs' L2s. b covers [0,512) per slice.
  const int sl = (bid & 7) >> 1;
  const int b  = ((bid & 1) << 8) | (bid >> 3);

  if (tid < NT) lt[tid] = t[tid];
  __syncthreads();

  // ---- Phase 1: basis for the block's 64 c's (tid < 64) ----
  if (tid < 64) {
    const int c = sl * 64 + tid;
    const float xv = x[b * IN_DIM + c];
    int i = 3 + (int)floorf((xv + 1.0f) * 32.0f);
    i = i < 3 ? 3 : (i > 66 ? 66 : i);
    while (i > 3 && xv < lt[i]) --i;
    while (i < 66 && xv >= lt[i + 1]) ++i;
    // i == clamp(searchsorted(t, xv, 'right') - 1, 3, 66)

    float N0 = 1.f, N1 = 0.f, N2 = 0.f, N3 = 0.f;
    // p = 1
    {
      const float l1 = xv - lt[i];
      const float r1 = lt[i + 1] - xv;
      const float tp = N0 / (r1 + l1);
      N1 = l1 * tp;
      N0 = r1 * tp;
    }
    // p = 2
    {
      const float l1 = xv - lt[i];
      const float l2 = xv - lt[i - 1];
      const float r1 = lt[i + 1] - xv;
      const float r2 = lt[i + 2] - xv;
      float saved = 0.f;
      const float tp0 = N0 / (r1 + l2);
      const float n0 = saved + r1 * tp0; saved = l2 * tp0;
      const float tp1 = N1 / (r2 + l1);
      const float n1 = saved + r2 * tp1; saved = l1 * tp1;
      N0 = n0; N1 = n1; N2 = saved;
    }
    // p = 3
    {
      const float l1 = xv - lt[i];
      const float l2 = xv - lt[i - 1];
      const float l3 = xv - lt[i - 2];
      const float r1 = lt[i + 1] - xv;
      const float r2 = lt[i + 2] - xv;
      const float r3 = lt[i + 3] - xv;
      float saved = 0.f;
      const float tp0 = N0 / (r1 + l3);
      const float n0 = saved + r1 * tp0; saved = l3 * tp0;
      const float tp1 = N1 / (r2 + l2);
      const float n1 = saved + r2 * tp1; saved = l2 * tp1;
      const float tp2 = N2 / (r3 + l1);
      const float n2 = saved + r3 * tp2; saved = l1 * tp2;
      N0 = n0; N1 = n1; N2 = n2; N3 = saved;
    }
    lyv[tid]   = make_float4(N0, N1, N2, N3);
    lys[tid]   = xv / (1.0f + expf(-xv));
    lbase[tid] = i - 3;
  }
  __syncthreads();

  // ---- Phase 2: gather-accumulate. thread = (oq in [0,64), cs in [0,4)) ----
  const int oq = tid & 63;   // float4 index over OUT_DIM
  const int cs = tid >> 6;   // 16 c's per thread
  const float4* __restrict__ w4 = (const float4*)w;  // idx: row*16384 + c*64 + oq

  float4 acc = make_float4(0.f, 0.f, 0.f, 0.f);
  const int cbeg = cs * 16;
  #pragma unroll 2
  for (int m = 0; m < 16; ++m) {
    const int cl = cbeg + m;
    const float4 yv = lyv[cl];       // LDS broadcast
    const float  ys = lys[cl];
    const int base  = lbase[cl];
    const float4* p = w4 + (sl * 64 + cl) * 64 + oq;
    const float4 a0 = p[(base + 0) * 16384];
    const float4 a1 = p[(base + 1) * 16384];
    const float4 a2 = p[(base + 2) * 16384];
    const float4 a3 = p[(base + 3) * 16384];
    const float4 a4 = p[67 * 16384];
    acc.x += yv.x * a0.x + yv.y * a1.x + yv.z * a2.x + yv.w * a3.x + ys * a4.x;
    acc.y += yv.x * a0.y + yv.y * a1.y + yv.z * a2.y + yv.w * a3.y + ys * a4.y;
    acc.z += yv.x * a0.z + yv.y * a1.z + yv.z * a2.z + yv.w * a3.z + ys * a4.z;
    acc.w += yv.x * a0.w + yv.y * a1.w + yv.z * a2.w + yv.w * a3.w + ys * a4.w;
  }

  // ---- Phase 3: reduce 4 c-slices in LDS, one atomicAdd set per output ----
  red4[cs][oq] = acc;
  __syncthreads();
  if (tid < 64) {
    const float4 p0 = red4[0][oq];
    const float4 p1 = red4[1][oq];
    const float4 p2 = red4[2][oq];
    const float4 p3 = red4[3][oq];
    float* op = out + b * OUT_DIM + oq * 4;
    atomicAdd(op + 0, (p0.x + p1.x) + (p2.x + p3.x));
    atomicAdd(op + 1, (p0.y + p1.y) + (p2.y + p3.y));
    atomicAdd(op + 2, (p0.z + p1.z) + (p2.z + p3.z));
    atomicAdd(op + 3, (p0.w + p1.w) + (p2.w + p3.w));
  }
}

extern "C" void kernel_launch(void* const* d_in, const int* in_sizes, int n_in,
                              void* d_out, int out_size, void* d_ws, size_t ws_size,
                              hipStream_t stream) {
  const float* x = (const float*)d_in[0];
  const float* w = (const float*)d_in[1];
  const float* t = (const float*)d_in[2];
  float* out = (float*)d_out;
  hipMemsetAsync(out, 0, (size_t)out_size * sizeof(float), stream);
  kan_gather_kernel<<<BATCH * 4, 256, 0, stream>>>(x, w, t, out);
}